// Round 7
// baseline (196.650 us; speedup 1.0000x reference)
//
#include <hip/hip_runtime.h>
#include <math.h>

typedef __attribute__((ext_vector_type(8))) _Float16 f16x8;
typedef __attribute__((ext_vector_type(4))) _Float16 f16x4;
typedef __attribute__((ext_vector_type(4))) float f32x4;
typedef __attribute__((ext_vector_type(16))) float f32x16;

#define MFMAH(a, b, c) __builtin_amdgcn_mfma_f32_16x16x32_f16((a), (b), (c), 0, 0, 0)
#define MFMA32(a, b, c) __builtin_amdgcn_mfma_f32_32x32x16_f16((a), (b), (c), 0, 0, 0)

// q pre-scale: 0.125 * log2(e)  (folds softmax exp->exp2 conversion into qk scale)
#define QSCALE 0.18033688011112042f
// softmax fixed offset in exp2 domain: 3 * log2(e)
#define SOFF 4.328085122666891f

// EMPIRICAL MATRIX (r7-r17 A/Bs, do not flip-flop):
//   gemm global mapping MUST keep 4-lanes-per-64B-segment
//   r12: gemm staging via global_load_lds w=16, linear LDS dest + inverse-swizzled
//        global source (rule #21). gemm_qkv 57.4 -> <53.6.
//   r13 FAILED (56->128us): direct-from-global K/V fragments are latency-bound.
//        K/V LDS staging REQUIRED.
//   r14 FAILED (56->62us): 16-row q-slices double per-wave K/V LDS reads; LDS-bound.
//        32 q-rows/wave is the right amortization.
//   r15 NEUTRAL (56->60us): 32x32 swapped-QK in-register P killed bank conflicts
//        and P round-trip; VALU/chain became the cost at 2 waves/SIMD.
//   r16 WIN (60.4->54.0): split-K wave groups -> 4/SIMD, linear combine.
//   r17 WIN (54.0->50.5): V seq-axis bit2<->3 permute at generation kills the
//        PV cross-lane fixup; setprio(1) around MFMA clusters. absmax unchanged.
// r18 (this round): gemm_proj was the worst-efficiency GEMM (128x64 tile:
//   8 MFMA per 6 ds_reads). Widen to the proven 128x128 qkv structure
//   (16 MFMA per 8 ds_reads, grid 32x8). Epilogue-only difference.

__device__ __forceinline__ void gl_lds16(const _Float16* g, _Float16* l) {
    __builtin_amdgcn_global_load_lds(
        (const __attribute__((address_space(1))) unsigned int*)g,
        (__attribute__((address_space(3))) unsigned int*)l, 16, 0, 0);
}

__device__ __forceinline__ unsigned pkh(float a, float b) {
    union { _Float16 h[2]; unsigned u; } x;
    x.h[0] = (_Float16)a;  // RNE converts (keep rounding identical to r12)
    x.h[1] = (_Float16)b;
    return x.u;
}

// ---------------- fused prep: cast x (float4), LDS-tiled weight transposes, rope ----------------
__global__ void prep_kernel(const float* __restrict__ x, const float* __restrict__ w_qkv,
                            const float* __restrict__ w_proj, _Float16* __restrict__ xb,
                            _Float16* __restrict__ wq, _Float16* __restrict__ wp,
                            float* __restrict__ ct, float* __restrict__ st,
                            float* __restrict__ xt) {
    __shared__ float tile[32][33];
    const int b = blockIdx.x, tid = threadIdx.x;
    if (b < 4096) {
        int i = (b * 256 + tid) * 4;
        float4 v = *(const float4*)&x[i];
        f16x4 h = {(_Float16)v.x, (_Float16)v.y, (_Float16)v.z, (_Float16)v.w};
        *(f16x4*)&xb[i] = h;
    } else if (b < 4096 + 3072 + 1024) {
        // weight transpose via 32x32 LDS tile: w [1024][C] -> wT [C][1024]
        int t, C;
        const float* src;
        _Float16* dst;
        if (b < 4096 + 3072) { t = b - 4096; C = 3072; src = w_qkv; dst = wq; }
        else                 { t = b - 4096 - 3072; C = 1024; src = w_proj; dst = wp; }
        const int tr = t & 31, tc = t >> 5;
        const int tx = tid & 31, ty = tid >> 5;
#pragma unroll
        for (int yy = 0; yy < 4; ++yy) {
            int r = ty + yy * 8;
            tile[r][tx] = src[(size_t)(tr * 32 + r) * C + tc * 32 + tx];
        }
        __syncthreads();
#pragma unroll
        for (int yy = 0; yy < 4; ++yy) {
            int r = ty + yy * 8;
            dst[(size_t)(tc * 32 + r) * 1024 + tr * 32 + tx] = (_Float16)tile[tx][r];
        }
    } else {
        int i = (b - 8192) * 256 + tid;
        int n = i >> 6, d = i & 63;
        int gi = n >> 6, gj = n & 63;
        int axis = d >> 5;
        int p = (d & 31) >> 1;
        float t = axis ? (float)gj : (float)gi;
        float half = axis ? 32.0f : 16.0f;
        float inv_freq = powf(10000.0f, -(float)p * (1.0f / 16.0f));
        float fr = t * inv_freq;
        float sbase = (2.0f * p + 12.8f) / 44.8f;
        float xs = powf(sbase, (t - half) * (1.0f / 64.0f));
        ct[i] = cosf(fr);
        st[i] = sinf(fr);
        xt[i] = xs;
    }
}

// ---------------- fp16 GEMM (128x128, BK=32, global_load_lds staging, XOR-swizzled source) -------
__global__ __launch_bounds__(256) void gemm_qkv_kernel(
    const _Float16* __restrict__ A_g, const _Float16* __restrict__ B_g,
    const float* __restrict__ bias, const float* __restrict__ ctab,
    const float* __restrict__ stab, const float* __restrict__ xtab,
    _Float16* __restrict__ qb, _Float16* __restrict__ kb, _Float16* __restrict__ vt) {
    __shared__ __align__(16) _Float16 Asm[4096];  // linear [row 128][slot 4][8]
    __shared__ __align__(16) _Float16 Bsm[4096];

    const int tid = threadIdx.x;
    const int lane = tid & 63, wave = tid >> 6;
    const int quad = lane >> 4, l16 = lane & 15;
    const int wm = wave >> 1, wn = wave & 1;
    const int m0 = blockIdx.x * 128, n0 = blockIdx.y * 128;

    f32x4 zero = {0.f, 0.f, 0.f, 0.f};
    f32x4 acc[4][4];
#pragma unroll
    for (int i = 0; i < 4; ++i)
#pragma unroll
        for (int j = 0; j < 4; ++j) acc[i][j] = zero;

    // chunk c -> row=c>>2, LDS slot=c&3 (linear dest). Global source quad is the
    // inverse-swizzled column chunk: g = slot ^ ((row>>1)&3). Read side applies
    // the same XOR, so fragment reads recover global quad `quad` unchanged.
    const int c1t = tid + 256;
    const int row0 = tid >> 2, s0 = tid & 3;
    const int row1 = c1t >> 2, s1 = c1t & 3;
    const int g0 = s0 ^ ((row0 >> 1) & 3);
    const int g1 = s1 ^ ((row1 >> 1) & 3);
    const _Float16* Ap0 = &A_g[(size_t)(m0 + row0) * 1024 + (g0 << 3)];
    const _Float16* Ap1 = &A_g[(size_t)(m0 + row1) * 1024 + (g1 << 3)];
    const _Float16* Bp0 = &B_g[(size_t)(n0 + row0) * 1024 + (g0 << 3)];
    const _Float16* Bp1 = &B_g[(size_t)(n0 + row1) * 1024 + (g1 << 3)];
    _Float16* La0 = &Asm[tid * 8];
    _Float16* La1 = &Asm[c1t * 8];
    _Float16* Lb0 = &Bsm[tid * 8];
    _Float16* Lb1 = &Bsm[c1t * 8];

    const int sw = (l16 >> 1) & 3;  // read-side swizzle (i-independent)

    for (int k0 = 0; k0 < 1024; k0 += 32) {
        __syncthreads();  // prior iteration's LDS reads complete
        gl_lds16(Ap0 + k0, La0);
        gl_lds16(Ap1 + k0, La1);
        gl_lds16(Bp0 + k0, Lb0);
        gl_lds16(Bp1 + k0, Lb1);
        __syncthreads();  // compiler drains vmcnt(0) here -> tile resident

        f16x8 af[4], bf[4];
#pragma unroll
        for (int i = 0; i < 4; ++i) {
            af[i] = *(const f16x8*)&Asm[(wm * 64 + i * 16 + l16) * 32 + ((quad ^ sw) << 3)];
            bf[i] = *(const f16x8*)&Bsm[(wn * 64 + i * 16 + l16) * 32 + ((quad ^ sw) << 3)];
        }
#pragma unroll
        for (int i = 0; i < 4; ++i)
#pragma unroll
            for (int j = 0; j < 4; ++j) acc[i][j] = MFMAH(af[i], bf[j], acc[i][j]);
    }

    float bj[4];
#pragma unroll
    for (int j = 0; j < 4; ++j) bj[j] = bias[n0 + wn * 64 + j * 16 + l16];

    if (n0 < 2048) {
        // q/k blocks: bias + xpos rope; q additionally scaled by 0.125*log2e
#pragma unroll
        for (int i = 0; i < 4; ++i) {
#pragma unroll
            for (int r = 0; r < 4; ++r) {
                const int row = m0 + wm * 64 + i * 16 + quad * 4 + r;
                const int b = row >> 11, nrow = row & 2047;
#pragma unroll
                for (int j = 0; j < 4; ++j) {
                    const int col = n0 + wn * 64 + j * 16 + l16;
                    float v = acc[i][j][r] + bj[j];
                    float partner = __shfl_xor(v, 1);  // rotate_half pair lives in lane^1
                    const int hh = (col >> 6) & 15;
                    const int d = col & 63;
                    const size_t o = ((size_t)(b * 16 + hh) * 2048 + nrow) * 64 + d;
                    float rh = (d & 1) ? partner : -partner;
                    const int ti = nrow * 64 + d;
                    float rv = v * ctab[ti] + rh * stab[ti];
                    float xs = xtab[ti];
                    if (col < 1024)
                        qb[o] = (_Float16)(rv * xs * QSCALE);
                    else
                        kb[o] = (_Float16)(rv / xs);
                }
            }
        }
    } else {
        // v blocks: bias only; write transposed vt[bh][d][n'] with n' = seq index
        // with bits 2<->3 SWAPPED (r17: pre-permutes V so attn's PV A-fragment
        // k-layout matches the QK output layout -> no cross-lane fixup in attn).
#pragma unroll
        for (int i = 0; i < 4; ++i) {
            const int row = m0 + wm * 64 + i * 16 + quad * 4;
            const int b = row >> 11, nrow = row & 2047;
            const int nrp = (nrow & ~12) | ((nrow & 4) << 1) | ((nrow & 8) >> 1);
#pragma unroll
            for (int j = 0; j < 4; ++j) {
                const int col = n0 + wn * 64 + j * 16 + l16;
                const int hh = (col >> 6) & 15;
                const int d = col & 63;
                f16x4 pv4;
#pragma unroll
                for (int r = 0; r < 4; ++r) pv4[r] = (_Float16)(acc[i][j][r] + bj[j]);
                *(f16x4*)&vt[((size_t)(b * 16 + hh) * 64 + d) * 2048 + nrp] = pv4;
            }
        }
    }
}

// ---------------- proj GEMM: r18 = same 128x128 structure as gemm_qkv, f32 epilogue --------------
__global__ __launch_bounds__(256) void gemm_proj_kernel(
    const _Float16* __restrict__ A_g, const _Float16* __restrict__ B_g,
    const float* __restrict__ bias, float* __restrict__ out) {
    __shared__ __align__(16) _Float16 Asm[4096];  // linear [row 128][slot 4][8]
    __shared__ __align__(16) _Float16 Bsm[4096];

    const int tid = threadIdx.x;
    const int lane = tid & 63, wave = tid >> 6;
    const int quad = lane >> 4, l16 = lane & 15;
    const int wm = wave >> 1, wn = wave & 1;
    const int m0 = blockIdx.x * 128, n0 = blockIdx.y * 128;

    f32x4 zero = {0.f, 0.f, 0.f, 0.f};
    f32x4 acc[4][4];
#pragma unroll
    for (int i = 0; i < 4; ++i)
#pragma unroll
        for (int j = 0; j < 4; ++j) acc[i][j] = zero;

    const int c1t = tid + 256;
    const int row0 = tid >> 2, s0 = tid & 3;
    const int row1 = c1t >> 2, s1 = c1t & 3;
    const int g0 = s0 ^ ((row0 >> 1) & 3);
    const int g1 = s1 ^ ((row1 >> 1) & 3);
    const _Float16* Ap0 = &A_g[(size_t)(m0 + row0) * 1024 + (g0 << 3)];
    const _Float16* Ap1 = &A_g[(size_t)(m0 + row1) * 1024 + (g1 << 3)];
    const _Float16* Bp0 = &B_g[(size_t)(n0 + row0) * 1024 + (g0 << 3)];
    const _Float16* Bp1 = &B_g[(size_t)(n0 + row1) * 1024 + (g1 << 3)];
    _Float16* La0 = &Asm[tid * 8];
    _Float16* La1 = &Asm[c1t * 8];
    _Float16* Lb0 = &Bsm[tid * 8];
    _Float16* Lb1 = &Bsm[c1t * 8];

    const int sw = (l16 >> 1) & 3;

    for (int k0 = 0; k0 < 1024; k0 += 32) {
        __syncthreads();
        gl_lds16(Ap0 + k0, La0);
        gl_lds16(Ap1 + k0, La1);
        gl_lds16(Bp0 + k0, Lb0);
        gl_lds16(Bp1 + k0, Lb1);
        __syncthreads();

        f16x8 af[4], bf[4];
#pragma unroll
        for (int i = 0; i < 4; ++i) {
            af[i] = *(const f16x8*)&Asm[(wm * 64 + i * 16 + l16) * 32 + ((quad ^ sw) << 3)];
            bf[i] = *(const f16x8*)&Bsm[(wn * 64 + i * 16 + l16) * 32 + ((quad ^ sw) << 3)];
        }
#pragma unroll
        for (int i = 0; i < 4; ++i)
#pragma unroll
            for (int j = 0; j < 4; ++j) acc[i][j] = MFMAH(af[i], bf[j], acc[i][j]);
    }

    float bj[4];
#pragma unroll
    for (int j = 0; j < 4; ++j) bj[j] = bias[n0 + wn * 64 + j * 16 + l16];
#pragma unroll
    for (int i = 0; i < 4; ++i)
#pragma unroll
        for (int r = 0; r < 4; ++r) {
            const int row = m0 + wm * 64 + i * 16 + quad * 4 + r;
#pragma unroll
            for (int j = 0; j < 4; ++j) {
                const int col = n0 + wn * 64 + j * 16 + l16;
                out[(size_t)row * 1024 + col] = acc[i][j][r] + bj[j];
            }
        }
}

// ---------------- flash attention: split-K wave groups, 32x32 swapped-QK, in-register P ----------
#define KLD 72   // K/V LDS row stride (fp16): 144B rows

__global__ __launch_bounds__(512) void attn_kernel(
    const _Float16* __restrict__ qb, const _Float16* __restrict__ kb,
    const _Float16* __restrict__ vt, _Float16* __restrict__ ao) {
    // 8 buffers x 64*KLD fp16 = 73728 B: K[grp][buf] then V[grp][buf]
    __shared__ __align__(16) _Float16 smem[8 * 64 * KLD];

    const int tid = threadIdx.x;
    const int lane = tid & 63, wave = tid >> 6;   // 8 waves
    const int w4 = wave & 3, wgrp = wave >> 2;    // q-slice, k-half
    const int l32 = lane & 31, hi = lane >> 5, hi8 = hi << 3;
    const int bh = blockIdx.x & 31, qt = blockIdx.x >> 5;  // same-bh blocks share an XCD/L2
    const size_t base = (size_t)bh * 2048 * 64;
    const int qrow0 = qt * 128 + w4 * 32;         // 32 q-rows per wave
    const int kbase = wgrp << 10;                 // this group's k-range start

    _Float16* K0 = &smem[(wgrp * 2 + 0) * 64 * KLD];
    _Float16* K1 = &smem[(wgrp * 2 + 1) * 64 * KLD];
    _Float16* V0 = &smem[(4 + wgrp * 2 + 0) * 64 * KLD];
    _Float16* V1 = &smem[(4 + wgrp * 2 + 1) * 64 * KLD];

    // Q as B-fragment of mfma(K,Q): col = q = l32, k-dim(d) = dc*16 + hi*8 + j
    f16x8 qf[4];
#pragma unroll
    for (int dc = 0; dc < 4; ++dc)
        qf[dc] = *(const f16x8*)&qb[base + (size_t)(qrow0 + l32) * 64 + dc * 16 + hi8];

    f32x16 moff16, zero16;
#pragma unroll
    for (int e = 0; e < 16; ++e) { moff16[e] = -SOFF; zero16[e] = 0.f; }
    f32x16 o0 = zero16, o1 = zero16;  // d-blocks 0..31 / 32..63
    float lsum = 0.f;

    // staging: each k-group's 256 threads stage its own 64x64 K and V tiles
    const int t256 = tid & 255;
    const int kr0 = t256 >> 3, ko0 = (t256 & 7) << 3;
    const int kr1 = kr0 + 32;
    f16x8 pk0, pk1, pv0, pv1;
    auto gload = [&](int kt) {
        pk0 = *(const f16x8*)&kb[base + (size_t)(kt + kr0) * 64 + ko0];
        pk1 = *(const f16x8*)&kb[base + (size_t)(kt + kr1) * 64 + ko0];
        pv0 = *(const f16x8*)&vt[((size_t)bh * 64 + kr0) * 2048 + kt + ko0];
        pv1 = *(const f16x8*)&vt[((size_t)bh * 64 + kr1) * 2048 + kt + ko0];
    };
    auto stage = [&](_Float16* Ks, _Float16* Vs) {
        *(f16x8*)&Ks[kr0 * KLD + ko0] = pk0;
        *(f16x8*)&Ks[kr1 * KLD + ko0] = pk1;
        *(f16x8*)&Vs[kr0 * KLD + ko0] = pv0;
        *(f16x8*)&Vs[kr1 * KLD + ko0] = pv1;
    };

    auto compute = [&](const _Float16* Ks, const _Float16* Vs) {
        // QK^T: A = K[32 k][16 d], B = Q  ->  D[k rows][q cols]; lane holds
        // s[kb][r] = S[q=l32][k = kb*32 + (r&3)+8*(r>>2)+4*hi]
        f32x16 s0 = moff16, s1 = moff16;
        __builtin_amdgcn_s_setprio(1);
#pragma unroll
        for (int dc = 0; dc < 4; ++dc) {
            f16x8 kf0 = *(const f16x8*)&Ks[l32 * KLD + dc * 16 + hi8];
            f16x8 kf1 = *(const f16x8*)&Ks[(32 + l32) * KLD + dc * 16 + hi8];
            s0 = MFMA32(kf0, qf[dc], s0);
            s1 = MFMA32(kf1, qf[dc], s1);
        }
        __builtin_amdgcn_s_setprio(0);
        float p0[16], p1[16];
#pragma unroll
        for (int e = 0; e < 16; ++e) {
            p0[e] = __builtin_amdgcn_exp2f(s0[e]);
            lsum += p0[e];
        }
#pragma unroll
        for (int e = 0; e < 16; ++e) {
            p1[e] = __builtin_amdgcn_exp2f(s1[e]);
            lsum += p1[e];
        }
        // PV per 16-k chunk c. V's seq axis was stored with k bits 2<->3 swapped,
        // which exactly matches the QK output reg order: A-frag slot j = own p[j]
        // of the chunk's 8-block. No cross-lane traffic.
        __builtin_amdgcn_s_setprio(1);
#pragma unroll
        for (int c = 0; c < 4; ++c) {
            const float* ps = (c < 2) ? p0 : p1;
            const int bo = (c & 1) * 8;
            union { unsigned w[4]; f16x8 v; } pf;
            pf.w[0] = pkh(ps[bo + 0], ps[bo + 1]);
            pf.w[1] = pkh(ps[bo + 2], ps[bo + 3]);
            pf.w[2] = pkh(ps[bo + 4], ps[bo + 5]);
            pf.w[3] = pkh(ps[bo + 6], ps[bo + 7]);
            f16x8 vf0 = *(const f16x8*)&Vs[l32 * KLD + c * 16 + hi8];
            f16x8 vf1 = *(const f16x8*)&Vs[(32 + l32) * KLD + c * 16 + hi8];
            o0 = MFMA32(pf.v, vf0, o0);
            o1 = MFMA32(pf.v, vf1, o1);
        }
        __builtin_amdgcn_s_setprio(0);
    };

    gload(kbase);
    stage(K0, V0);
    gload(kbase + 64);
    __syncthreads();

    for (int it = 0; it < 16; it += 2) {
        stage(K1, V1);                              // local tile it+1
        if (it + 2 < 16) gload(kbase + (it + 2) * 64);
        compute(K0, V0);                            // local tile it
        __syncthreads();
        if (it + 2 < 16) stage(K0, V0);             // local tile it+2
        if (it + 3 < 16) gload(kbase + (it + 3) * 64);
        compute(K1, V1);                            // local tile it+1
        __syncthreads();
    }

    // within-wave k-half reduce (lane l32 <-> lane^32 hold complementary k's)
    float vsum = lsum + __shfl_xor(lsum, 32);

    // cross-group combine: group 1 deposits partial o/lsum; group 0 adds.
    // stride 33 floats -> bank = (lane + idx) % 32, conflict-free.
    float* cb = (float*)smem;
    if (wgrp == 1) {
        float* p = &cb[(w4 * 64 + lane) * 33];
#pragma unroll
        for (int r = 0; r < 16; ++r) { p[r] = o0[r]; p[16 + r] = o1[r]; }
        p[32] = vsum;
    }
    __syncthreads();
    if (wgrp == 0) {
        const float* p = &cb[(w4 * 64 + lane) * 33];
#pragma unroll
        for (int r = 0; r < 16; ++r) { o0[r] += p[r]; o1[r] += p[16 + r]; }
        vsum += p[32];

        float vinv = 1.0f / vsum;
        float linv[16];
#pragma unroll
        for (int r = 0; r < 16; ++r)
            linv[r] = __shfl(vinv, (r & 3) + 8 * (r >> 2) + 4 * hi);

        const int b = bh >> 4, hh = bh & 15;
#pragma unroll
        for (int r = 0; r < 16; ++r) {
            const int qrow = qrow0 + (r & 3) + 8 * (r >> 2) + 4 * hi;
            const size_t oi = ((size_t)(b * 2048 + qrow)) * 1024 + hh * 64 + l32;
            ao[oi] = (_Float16)(o0[r] * linv[r]);
            ao[oi + 32] = (_Float16)(o1[r] * linv[r]);
        }
    }
}

// ---------------- launcher ----------------
extern "C" void kernel_launch(void* const* d_in, const int* in_sizes, int n_in,
                              void* d_out, int out_size, void* d_ws, size_t ws_size,
                              hipStream_t stream) {
    const float* x = (const float*)d_in[0];
    const float* w_qkv = (const float*)d_in[1];
    const float* b_qkv = (const float*)d_in[2];
    const float* w_proj = (const float*)d_in[3];
    const float* b_proj = (const float*)d_in[4];
    float* out = (float*)d_out;

    char* ws = (char*)d_ws;
    size_t off = 0;
    auto take = [&](size_t bytes) { char* p = ws + off; off += bytes; return p; };
    _Float16* xbuf   = (_Float16*)take(8388608);   // x fp16 [4096][1024]
    _Float16* wqkvT  = (_Float16*)take(6291456);   // w_qkv^T [3072][1024]
    _Float16* wprojT = (_Float16*)take(2097152);   // w_proj^T [1024][1024]
    _Float16* qbuf   = (_Float16*)take(8388608);   // q (rope, *0.125*log2e)
    _Float16* kbuf   = (_Float16*)take(8388608);
    _Float16* vtbuf  = (_Float16*)take(8388608);   // v^T [bh][d][n bit2<->3], by gemm_qkv
    float* ctab      = (float*)take(524288);
    float* stab      = (float*)take(524288);
    float* xtab      = (float*)take(524288);
    _Float16* ao = xbuf;  // x dead after gemm_qkv; attn output reuses it

    prep_kernel<<<8704, 256, 0, stream>>>(x, w_qkv, w_proj, xbuf, wqkvT, wprojT,
                                          ctab, stab, xtab);
    gemm_qkv_kernel<<<dim3(32, 24), 256, 0, stream>>>(xbuf, wqkvT, b_qkv,
                                                      ctab, stab, xtab, qbuf, kbuf, vtbuf);
    attn_kernel<<<512, 512, 0, stream>>>(qbuf, kbuf, vtbuf, ao);
    gemm_proj_kernel<<<dim3(32, 8), 256, 0, stream>>>(ao, wprojT, b_proj, out);
}